// Round 6
// baseline (428.770 us; speedup 1.0000x reference)
//
#include <hip/hip_runtime.h>
#include <hip/hip_bf16.h>

// NonLocalBlock: B=8, C=512, CI=256, H=W=56, N=3136.
// Round-6: conflict-free LDS via fragment-order global_load_lds gather
// (per-lane source addresses, wave-contiguous b128 frag reads) in both
// attn and gemm_bt; gemm_bt also gets double-buffer + K-step 64.
// Other kernels identical to round 5 (passed, 392 us).

typedef unsigned short u16;
typedef unsigned int u32;
typedef __attribute__((ext_vector_type(8))) short short8;   // 8 bf16
typedef __attribute__((ext_vector_type(4))) float floatx4;

#define B_   8
#define C_   512
#define CI_  256
#define N_   3136
#define BN_  25088   // B_*N_

__device__ __forceinline__ u16 f2b(float f) {
    return __builtin_bit_cast(u16, __float2bfloat16(f));
}
__device__ __forceinline__ float b2f(u16 u) {
    return __bfloat162float(__builtin_bit_cast(__hip_bfloat16, u));
}
__device__ __forceinline__ floatx4 mfma16(short8 a, short8 b, floatx4 c) {
    return __builtin_amdgcn_mfma_f32_16x16x32_bf16(a, b, c, 0, 0, 0);
}
// async global->LDS DMA, 16 B/lane; dest = wave-uniform base + lane*16,
// source address may be fully per-lane (gather).
__device__ __forceinline__ void gload_lds16(const u16* g, u16* l) {
    __builtin_amdgcn_global_load_lds(
        (const __attribute__((address_space(1))) u32*)g,
        (__attribute__((address_space(3))) u32*)l, 16, 0, 0);
}

// ---------------------------------------------------------------------------
// Runtime dtype detection (picked bf16 in rounds 3-5; kept for safety).
// ---------------------------------------------------------------------------
__global__ void detect_dtype(const u32* __restrict__ xw, int* __restrict__ flag)
{
    __shared__ int cnt;
    if (threadIdx.x == 0) cnt = 0;
    __syncthreads();
    int c = 0;
    for (int i = 0; i < 16; ++i) {
        u32 w = xw[threadIdx.x * 16 + i];
        u32 e = (w >> 7) & 0xFF;
        c += (e >= 118 && e <= 130) ? 1 : 0;
    }
    atomicAdd(&cnt, c);
    __syncthreads();
    if (threadIdx.x == 0) *flag = (2 * cnt > 4096) ? 1 : 0;
}

// ---------------------------------------------------------------------------
// Convert the 10 parameter arrays into canonical bf16, flag-branched.
// ---------------------------------------------------------------------------
__global__ __launch_bounds__(256) void convert_params(
    const void* tw, const void* tb, const void* pw, const void* pb,
    const void* gw, const void* gbi, const void* ww, const void* wb,
    const void* gamma, const void* beta,
    u16* __restrict__ dst, const int* __restrict__ flag)
{
    const void* srcs[10] = {tw, tb, pw, pb, gw, gbi, ww, wb, gamma, beta};
    const int ns[10] = {131072, 256, 131072, 256, 131072, 256, 131072, 512, 512, 512};
    int seg = blockIdx.y;
    int off = 0;
    for (int s = 0; s < 10; ++s) { if (s == seg) break; off += ns[s]; }
    const void* src = srcs[seg];
    int n = ns[seg];
    int i0 = (blockIdx.x * 256 + threadIdx.x) * 8;
    if (i0 >= n) return;
    const int fl = *flag;
    u16* d = dst + off;
    for (int k = 0; k < 8; ++k) {
        int i = i0 + k;
        if (i < n)
            d[i] = fl ? ((const u16*)src)[i] : f2b(((const float*)src)[i]);
    }
}

// ---------------------------------------------------------------------------
// x ingest + transpose: x [b,C,N] (fp32 or bf16) -> xT [b,N,C] bf16.
// ---------------------------------------------------------------------------
__global__ __launch_bounds__(256) void transpose_x(
    const void* __restrict__ in, u16* __restrict__ out,
    const int* __restrict__ flag)
{
    __shared__ u16 tile[64][68];
    const int fl = *flag;
    const int t = threadIdx.x;
    const long base = (long)blockIdx.z * (long)C_ * (long)N_;
    const int c0 = blockIdx.x * 64, r0 = blockIdx.y * 64;
    const int lr = t >> 3;
    const int lc = (t & 7) * 8;
#pragma unroll
    for (int j = 0; j < 2; ++j) {
        int rr = lr + 32 * j;
        long eoff = base + (long)(r0 + rr) * N_ + c0 + lc;
        u16 v[8] __attribute__((aligned(16)));
        if (fl) {
            const u16* pi = (const u16*)in + eoff;
            *(uint64_t*)&v[0] = *(const uint64_t*)pi;
            *(uint64_t*)&v[4] = *(const uint64_t*)(pi + 4);
        } else {
            const float* pi = (const float*)in + eoff;
            floatx4 a = *(const floatx4*)pi;
            floatx4 b4 = *(const floatx4*)(pi + 4);
#pragma unroll
            for (int k = 0; k < 4; ++k) { v[k] = f2b(a[k]); v[4 + k] = f2b(b4[k]); }
        }
        *(uint64_t*)&tile[rr][lc] = *(const uint64_t*)&v[0];
        *(uint64_t*)&tile[rr][lc + 4] = *(const uint64_t*)&v[4];
    }
    __syncthreads();
#pragma unroll
    for (int j = 0; j < 2; ++j) {
        int oc = lr + 32 * j;
        int ob = (t & 7) * 8;
        u16 vals[8] __attribute__((aligned(16)));
#pragma unroll
        for (int k = 0; k < 8; ++k) vals[k] = tile[ob + k][oc];
        u16* po = out + (long)blockIdx.z * N_ * C_ + (long)(c0 + oc) * C_ + r0 + ob;
        *(uint64_t*)po = *(const uint64_t*)vals;
        *(uint64_t*)(po + 4) = *(const uint64_t*)(vals + 4);
    }
}

// ---------------------------------------------------------------------------
// bf16 64x64 tile transpose: in [z][R][Cc] -> out [z][Cc][R]
// ---------------------------------------------------------------------------
__global__ __launch_bounds__(256) void transpose64(
    const u16* __restrict__ in, u16* __restrict__ out, int R, int Cc)
{
    __shared__ u16 tile[64][68];
    const int t = threadIdx.x;
    const long base = (long)blockIdx.z * (long)R * (long)Cc;
    const int c0 = blockIdx.x * 64, r0 = blockIdx.y * 64;
    const int lr = t >> 3;
    const int lc = (t & 7) * 8;
#pragma unroll
    for (int j = 0; j < 2; ++j) {
        int rr = lr + 32 * j;
        const u16* pi = in + base + (long)(r0 + rr) * Cc + c0 + lc;
        *(uint64_t*)&tile[rr][lc] = *(const uint64_t*)pi;
        *(uint64_t*)&tile[rr][lc + 4] = *(const uint64_t*)(pi + 4);
    }
    __syncthreads();
#pragma unroll
    for (int j = 0; j < 2; ++j) {
        int oc = lr + 32 * j;
        int ob = (t & 7) * 8;
        u16 vals[8] __attribute__((aligned(16)));
#pragma unroll
        for (int k = 0; k < 8; ++k) vals[k] = tile[ob + k][oc];
        u16* po = out + base + (long)(c0 + oc) * R + r0 + ob;
        *(uint64_t*)po = *(const uint64_t*)vals;
        *(uint64_t*)(po + 4) = *(const uint64_t*)(vals + 4);
    }
}

// ---------------------------------------------------------------------------
// GEMM (B^T) v2: fragment-order DMA staging, double-buffered, K-step 64.
// frag[ks][rg][lane] = M[base + rg*16 + lx][k0 + ks*32 + q*8 ..]; frag reads
// are wave-contiguous 1KB ds_read_b128 (conflict-free by construction).
// grid = (M/64, ncols/64, batch), block = 256 (4 waves 2x2).
// ---------------------------------------------------------------------------
template<int K>
__global__ __launch_bounds__(256, 4) void gemm_bt(
    const u16* __restrict__ A, long a_bstride,
    const u16* __restrict__ Bt,
    const u16* __restrict__ bias,
    u16* __restrict__ Out, long out_bstride,
    int ncols)
{
    __shared__ __attribute__((aligned(16))) u16 Asf[2][2][4][64][8];
    __shared__ __attribute__((aligned(16))) u16 Bsf[2][2][4][64][8];

    const int t = threadIdx.x;
    const int wave = t >> 6, lane = t & 63;
    const int q = lane >> 4, lx = lane & 15;
    const int m0 = blockIdx.x * 64;
    const int n0c = blockIdx.y * 64;
    const int b = blockIdx.z;
    const u16* Ab = A + (long)b * a_bstride;

    floatx4 zero4 = {0.f, 0.f, 0.f, 0.f};
    floatx4 acc[2][2];
#pragma unroll
    for (int i = 0; i < 2; ++i)
#pragma unroll
        for (int j = 0; j < 2; ++j) acc[i][j] = zero4;

    // wave w stages A rowgroup w and B colgroup w, both k-halves
    auto stage = [&](int buf, int k0) {
#pragma unroll
        for (int ks = 0; ks < 2; ++ks) {
            gload_lds16(Ab + (long)(m0 + wave * 16 + lx) * K + k0 + ks * 32 + q * 8,
                        &Asf[buf][ks][wave][0][0]);
            gload_lds16(Bt + (long)(n0c + wave * 16 + lx) * K + k0 + ks * 32 + q * 8,
                        &Bsf[buf][ks][wave][0][0]);
        }
    };

    stage(0, 0);
    const int rg = (wave >> 1) * 2, cg = (wave & 1) * 2;
    const int NS = K / 64;
    for (int s = 0; s < NS; ++s) {
        const int buf = s & 1;
        __syncthreads();                 // drains DMA (vmcnt0) + block sync
        if (s + 1 < NS) stage(buf ^ 1, (s + 1) * 64);
#pragma unroll
        for (int ks = 0; ks < 2; ++ks) {
            short8 af0 = *(const short8*)&Asf[buf][ks][rg][lane][0];
            short8 af1 = *(const short8*)&Asf[buf][ks][rg + 1][lane][0];
            short8 bf0 = *(const short8*)&Bsf[buf][ks][cg][lane][0];
            short8 bf1 = *(const short8*)&Bsf[buf][ks][cg + 1][lane][0];
            acc[0][0] = mfma16(af0, bf0, acc[0][0]);
            acc[0][1] = mfma16(af0, bf1, acc[0][1]);
            acc[1][0] = mfma16(af1, bf0, acc[1][0]);
            acc[1][1] = mfma16(af1, bf1, acc[1][1]);
        }
    }

    // C/D layout: col=lane&15, row=(lane>>4)*4+reg  [m89/m91]
    const int wr = (wave >> 1) * 32, wc = (wave & 1) * 32;
#pragma unroll
    for (int i = 0; i < 2; ++i) {
#pragma unroll
        for (int j = 0; j < 2; ++j) {
            int col = n0c + wc + 16 * j + lx;
            float bv = b2f(bias[col]);
#pragma unroll
            for (int r = 0; r < 4; ++r) {
                int row = m0 + wr + 16 * i + q * 4 + r;
                Out[(long)b * out_bstride + (long)row * ncols + col] =
                    f2b(acc[i][j][r] + bv);
            }
        }
    }
}

// ---------------------------------------------------------------------------
// Fused attention v4: fragment-order DMA tiles (conflict-free b128 reads).
// Block = 128 Q-rows (4 waves x 32), m-step 32, z-split 2.
// psf[buf][kk][mh][lane] = phi[m0+mh*16+lx][kk*32+q*8..]   (16 KB/buf)
// gsf[buf][ct][lane]     = gT[ct*16+lx][m0+q*8..]          (16 KB/buf)
// Ps[4][32][40] per-wave P C->A round-trip. grid = (25, B, 2), block 256.
// ---------------------------------------------------------------------------
__global__ __launch_bounds__(256, 2) void attn(
    const u16* __restrict__ theta,   // [B][N][CI]
    const u16* __restrict__ phi,     // [B][N][CI]
    const u16* __restrict__ gT,      // [B][CI][N]
    u16* __restrict__ ypart,         // [2][B][N][CI] unnormalized (= d_out)
    float* __restrict__ lpart)       // [2][B][N] row exp-sums
{
    __shared__ __attribute__((aligned(16))) u16 psf[2][8][2][64][8];
    __shared__ __attribute__((aligned(16))) u16 gsf[2][16][64][8];
    __shared__ __attribute__((aligned(16))) u16 Ps[4][32][40];

    const int t = threadIdx.x;
    const int wave = t >> 6, lane = t & 63;
    const int q = lane >> 4, lx = lane & 15;
    const int b = blockIdx.y;
    const int z = blockIdx.z;
    const int n0w = blockIdx.x * 128 + wave * 32;
    const bool valid = n0w < N_;
    const u16* thb = theta + (long)b * N_ * CI_;
    const u16* phb = phi + (long)b * N_ * CI_;
    const u16* gb = gT + (long)b * CI_ * N_;

    // persistent theta A-frags: 2 row-halves x 8 k-chunks (64 VGPR)
    short8 tf[2][8];
#pragma unroll
    for (int h = 0; h < 2; ++h) {
        int trow = n0w + h * 16 + lx;
        if (trow >= N_) trow = N_ - 1;
#pragma unroll
        for (int kk = 0; kk < 8; ++kk)
            tf[h][kk] = *(const short8*)(thb + (long)trow * CI_ + kk * 32 + q * 8);
    }

    floatx4 zero4 = {0.f, 0.f, 0.f, 0.f};
    floatx4 yacc[2][16];
#pragma unroll
    for (int h = 0; h < 2; ++h)
#pragma unroll
        for (int i = 0; i < 16; ++i) yacc[h][i] = zero4;
    floatx4 lacc[2] = {zero4, zero4};
    const short8 ones = {0x3F80, 0x3F80, 0x3F80, 0x3F80,
                         0x3F80, 0x3F80, 0x3F80, 0x3F80};

    const int mbeg = z * (N_ / 2);

    // fragment-order gather: 8 DMA insts per wave per step
    auto stage = [&](int buf, int m0) {
#pragma unroll
        for (int i = 0; i < 2; ++i) {
            int kc = wave * 2 + i;
#pragma unroll
            for (int h = 0; h < 2; ++h)
                gload_lds16(phb + (long)(m0 + h * 16 + lx) * CI_ + kc * 32 + q * 8,
                            &psf[buf][kc][h][0][0]);
        }
#pragma unroll
        for (int j4 = 0; j4 < 4; ++j4) {
            int ct = wave * 4 + j4;
            gload_lds16(gb + (long)(ct * 16 + lx) * N_ + m0 + q * 8,
                        &gsf[buf][ct][0][0]);
        }
    };

    stage(0, mbeg);
    const int NSTEP = (N_ / 2) / 32;     // 49
    for (int s = 0; s < NSTEP; ++s) {
        const int buf = s & 1;
        __syncthreads();                 // drains DMA (vmcnt0) + block sync
        if (s + 1 < NSTEP) stage(buf ^ 1, mbeg + (s + 1) * 32);

        // ---- S = theta . phi^T : 16 conflict-free b128 reads, 32 MFMAs ----
        floatx4 sacc[2][2];
        sacc[0][0] = zero4; sacc[0][1] = zero4;
        sacc[1][0] = zero4; sacc[1][1] = zero4;
#pragma unroll
        for (int kk = 0; kk < 8; ++kk) {
            short8 bf0 = *(const short8*)&psf[buf][kk][0][lane][0];
            short8 bf1 = *(const short8*)&psf[buf][kk][1][lane][0];
            sacc[0][0] = mfma16(tf[0][kk], bf0, sacc[0][0]);
            sacc[1][0] = mfma16(tf[1][kk], bf0, sacc[1][0]);
            sacc[0][1] = mfma16(tf[0][kk], bf1, sacc[0][1]);
            sacc[1][1] = mfma16(tf[1][kk], bf1, sacc[1][1]);
        }

        // ---- exp + pack P to A-layout via per-wave LDS ----
#pragma unroll
        for (int h = 0; h < 2; ++h)
#pragma unroll
            for (int mh = 0; mh < 2; ++mh)
#pragma unroll
                for (int r = 0; r < 4; ++r) {
                    float e = __expf(fminf(sacc[h][mh][r], 60.f));
                    Ps[wave][h * 16 + q * 4 + r][mh * 16 + lx] = f2b(e);
                }
        __builtin_amdgcn_wave_barrier();
        short8 pA0 = *(const short8*)&Ps[wave][lx][q * 8];
        short8 pA1 = *(const short8*)&Ps[wave][16 + lx][q * 8];
        __builtin_amdgcn_wave_barrier();

        // ---- PV: 16 conflict-free b128 reads, 32+2 MFMAs ----
#pragma unroll
        for (int ct = 0; ct < 16; ++ct) {
            short8 gf = *(const short8*)&gsf[buf][ct][lane][0];
            yacc[0][ct] = mfma16(pA0, gf, yacc[0][ct]);
            yacc[1][ct] = mfma16(pA1, gf, yacc[1][ct]);
        }
        lacc[0] = mfma16(pA0, ones, lacc[0]);
        lacc[1] = mfma16(pA1, ones, lacc[1]);
    }

    if (valid) {
        u16* yb = ypart + (long)z * B_ * N_ * CI_ + (long)b * N_ * CI_;
#pragma unroll
        for (int h = 0; h < 2; ++h)
#pragma unroll
            for (int ct = 0; ct < 16; ++ct)
#pragma unroll
                for (int r = 0; r < 4; ++r)
                    yb[(long)(n0w + h * 16 + q * 4 + r) * CI_ + ct * 16 + lx] =
                        f2b(yacc[h][ct][r]);
        if (lx == 0) {
#pragma unroll
            for (int h = 0; h < 2; ++h)
#pragma unroll
                for (int r = 0; r < 4; ++r)
                    lpart[(long)z * BN_ + (long)b * N_ + n0w + h * 16 + q * 4 + r] =
                        lacc[h][r];
        }
    }
}

// ---------------------------------------------------------------------------
// y = (y0 + y1) / (l0 + l1);  grid = BN_*32/256 = 3136 blocks
// ---------------------------------------------------------------------------
__global__ __launch_bounds__(256) void attn_combine(
    const u16* __restrict__ ypart, const float* __restrict__ lpart,
    u16* __restrict__ y)
{
    long tt = (long)blockIdx.x * 256 + threadIdx.x;
    long row = tt >> 5;
    int cb = (int)(tt & 31) * 8;
    float l = lpart[row] + lpart[BN_ + row];
    float rl = 1.0f / l;
    const u16* p0 = ypart + row * CI_ + cb;
    const u16* p1 = p0 + (long)B_ * N_ * CI_;
    short8 v0 = *(const short8*)p0;
    short8 v1 = *(const short8*)p1;
    u16 ov[8] __attribute__((aligned(16)));
#pragma unroll
    for (int j = 0; j < 8; ++j)
        ov[j] = f2b((b2f(((const u16*)&v0)[j]) + b2f(((const u16*)&v1)[j])) * rl);
    *(short8*)(y + row * CI_ + cb) = *(const short8*)ov;
}

// ---------------------------------------------------------------------------
// BN stats over bf16 wy [b,N,C]: per-block partials + atomics.
// ---------------------------------------------------------------------------
__global__ void zero_stats(float* stats) {
    stats[threadIdx.x] = 0.f;
    stats[threadIdx.x + 256] = 0.f;
    stats[threadIdx.x + 512] = 0.f;
    stats[threadIdx.x + 768] = 0.f;
}

__global__ __launch_bounds__(256) void bn_stats(
    const u16* __restrict__ wy, float* __restrict__ stats)
{
    const int t = threadIdx.x;
    const long row0 = (long)blockIdx.x * 256;
    float s0 = 0.f, s1 = 0.f, q0 = 0.f, q1 = 0.f;
    for (int r = 0; r < 256; ++r) {
        const u16* p = wy + (row0 + r) * C_;
        float a = b2f(p[t]), b = b2f(p[t + 256]);
        s0 += a; q0 += a * a;
        s1 += b; q1 += b * b;
    }
    atomicAdd(&stats[t], s0);
    atomicAdd(&stats[t + 256], s1);
    atomicAdd(&stats[C_ + t], q0);
    atomicAdd(&stats[C_ + t + 256], q1);
}

// ---------------------------------------------------------------------------
// out[b][c][n] = (wy[b][n][c]-mean)*rstd*gamma + beta + x[b][c][n]
// ---------------------------------------------------------------------------
__global__ __launch_bounds__(256) void bn_apply(
    const u16* __restrict__ wy, const void* __restrict__ xv,
    const u16* __restrict__ gamma, const u16* __restrict__ beta,
    const float* __restrict__ stats, void* __restrict__ outv,
    const int* __restrict__ flag)
{
    __shared__ float tile[64][65];
    const int fl = *flag;
    const int t = threadIdx.x;
    const int nb0 = blockIdx.x * 64;
    const int c0 = blockIdx.y * 64;
    const int b = blockIdx.z;
#pragma unroll
    for (int j = 0; j < 4; ++j) {
        int row = (t >> 4) + 16 * j;
        int col = (t & 15) * 4;
        const u16* p = wy + ((long)b * N_ + nb0 + row) * C_ + c0 + col;
        u16 lv[4] __attribute__((aligned(8)));
        *(uint64_t*)lv = *(const uint64_t*)p;
#pragma unroll
        for (int k = 0; k < 4; ++k) tile[row][col + k] = b2f(lv[k]);
    }
    __syncthreads();
    const float inv = 1.0f / (float)BN_;
#pragma unroll
    for (int it = 0; it < 8; ++it) {
        int oc = (t >> 5) + 8 * it;
        int on = (t & 31) * 2;
        int c = c0 + oc;
        float mean = stats[c] * inv;
        float var = stats[C_ + c] * inv - mean * mean;
        float rstd = rsqrtf(var + 1e-5f);
        float sc = b2f(gamma[c]) * rstd;
        float sh = b2f(beta[c]) - mean * sc;
        long base = ((long)b * C_ + c) * N_ + nb0 + on;
        float v0 = tile[on][oc] * sc + sh;
        float v1 = tile[on + 1][oc] * sc + sh;
        if (fl) {
            v0 += b2f(((const u16*)xv)[base]);
            v1 += b2f(((const u16*)xv)[base + 1]);
            ((u16*)outv)[base] = f2b(v0);
            ((u16*)outv)[base + 1] = f2b(v1);
        } else {
            v0 += ((const float*)xv)[base];
            v1 += ((const float*)xv)[base + 1];
            ((float*)outv)[base] = v0;
            ((float*)outv)[base + 1] = v1;
        }
    }
}

// ---------------------------------------------------------------------------
extern "C" void kernel_launch(void* const* d_in, const int* in_sizes, int n_in,
                              void* d_out, int out_size, void* d_ws, size_t ws_size,
                              hipStream_t stream)
{
    (void)in_sizes; (void)n_in; (void)out_size; (void)ws_size;

    const size_t S = 12845056;               // one [B,N,CI] bf16 slab (bytes)
    char* base = (char*)d_ws;
    u16*   xT    = (u16*)(base);             // [0, 2S)   steps 1-2
    u16*   gT    = (u16*)(base);             // [0, S)    steps 3-4
    u16*   y     = (u16*)(base + S);         // [S, 2S)   steps 5-6
    u16*   th    = (u16*)(base + 2 * S);     // [2S, 3S)  steps 2-4
    u16*   ph    = (u16*)(base + 3 * S);     // [3S, 4S)  steps 2-4
    u16*   wy    = (u16*)(base + 2 * S);     // [2S, 4S)  steps 6-8
    u16*   gn    = (u16*)(base + 4 * S);     // [4S, 5S)  steps 2-3
    float* lpart = (float*)(base + 5 * S);
    float* stats = (float*)(base + 5 * S + (size_t)2 * BN_ * 4);
    u16*   cw    = (u16*)(base + 5 * S + (size_t)2 * BN_ * 4 + 4096);
    int*   flag  = (int*)(base + 5 * S + (size_t)2 * BN_ * 4 + 4096 + 1055744);

    u16* ctw = cw;               u16* ctb = cw + 131072;
    u16* cpw = ctb + 256;        u16* cpb = cpw + 131072;
    u16* cgw = cpb + 256;        u16* cgb = cgw + 131072;
    u16* cww = cgb + 256;        u16* cwb = cww + 131072;
    u16* cga = cwb + 512;        u16* cbe = cga + 512;

    u16* ypart = (u16*)d_out;    // scratch, dead before bn_apply overwrites

    detect_dtype<<<1, 256, 0, stream>>>((const u32*)d_in[0], flag);
    convert_params<<<dim3(64, 10), 256, 0, stream>>>(
        d_in[1], d_in[2], d_in[3], d_in[4], d_in[5], d_in[6], d_in[7],
        d_in[8], d_in[9], d_in[10], cw, flag);

    transpose_x<<<dim3(N_ / 64, C_ / 64, B_), 256, 0, stream>>>(d_in[0], xT, flag);

    gemm_bt<C_><<<dim3(N_ / 64, CI_ / 64, B_), 256, 0, stream>>>(
        xT, (long)N_ * C_, ctw, ctb, th, (long)N_ * CI_, CI_);
    gemm_bt<C_><<<dim3(N_ / 64, CI_ / 64, B_), 256, 0, stream>>>(
        xT, (long)N_ * C_, cpw, cpb, ph, (long)N_ * CI_, CI_);
    gemm_bt<C_><<<dim3(N_ / 64, CI_ / 64, B_), 256, 0, stream>>>(
        xT, (long)N_ * C_, cgw, cgb, gn, (long)N_ * CI_, CI_);

    transpose64<<<dim3(CI_ / 64, N_ / 64, B_), 256, 0, stream>>>(gn, gT, N_, CI_);

    attn<<<dim3(25, B_, 2), 256, 0, stream>>>(th, ph, gT, ypart, lpart);

    attn_combine<<<dim3((BN_ * 32) / 256), 256, 0, stream>>>(ypart, lpart, y);

    gemm_bt<CI_><<<dim3(N_ / 64, C_ / 64, B_), 256, 0, stream>>>(
        y, (long)N_ * CI_, cww, cwb, wy, (long)N_ * C_, C_);

    zero_stats<<<1, 256, 0, stream>>>(stats);
    bn_stats<<<BN_ / 256, 256, 0, stream>>>(wy, stats);

    bn_apply<<<dim3(N_ / 64, C_ / 64, B_), 256, 0, stream>>>(
        wy, d_in[0], cga, cbe, stats, d_out, flag);
}

// Round 7
// 382.800 us; speedup vs baseline: 1.1201x; 1.1201x over previous
//
#include <hip/hip_runtime.h>
#include <hip/hip_bf16.h>

// NonLocalBlock: B=8, C=512, CI=256, H=W=56, N=3136.
// Round-7: (1) gemm128 — m97-style 128x128 tile, fragment-order DMA,
// dbuf, 3-projection fused launch (grid z = weight set); (2) attn = r6
// conflict-free layout + r5 batched S-phase frag prefetch.

typedef unsigned short u16;
typedef unsigned int u32;
typedef __attribute__((ext_vector_type(8))) short short8;   // 8 bf16
typedef __attribute__((ext_vector_type(4))) float floatx4;

#define B_   8
#define C_   512
#define CI_  256
#define N_   3136
#define BN_  25088   // B_*N_

__device__ __forceinline__ u16 f2b(float f) {
    return __builtin_bit_cast(u16, __float2bfloat16(f));
}
__device__ __forceinline__ float b2f(u16 u) {
    return __bfloat162float(__builtin_bit_cast(__hip_bfloat16, u));
}
__device__ __forceinline__ floatx4 mfma16(short8 a, short8 b, floatx4 c) {
    return __builtin_amdgcn_mfma_f32_16x16x32_bf16(a, b, c, 0, 0, 0);
}
// async global->LDS DMA, 16 B/lane; LDS dest = wave-uniform base + lane*16,
// source address fully per-lane (gather).
__device__ __forceinline__ void gload_lds16(const u16* g, u16* l) {
    __builtin_amdgcn_global_load_lds(
        (const __attribute__((address_space(1))) u32*)g,
        (__attribute__((address_space(3))) u32*)l, 16, 0, 0);
}

// ---------------------------------------------------------------------------
// Runtime dtype detection (picked bf16 in rounds 3-6; kept for safety).
// ---------------------------------------------------------------------------
__global__ void detect_dtype(const u32* __restrict__ xw, int* __restrict__ flag)
{
    __shared__ int cnt;
    if (threadIdx.x == 0) cnt = 0;
    __syncthreads();
    int c = 0;
    for (int i = 0; i < 16; ++i) {
        u32 w = xw[threadIdx.x * 16 + i];
        u32 e = (w >> 7) & 0xFF;
        c += (e >= 118 && e <= 130) ? 1 : 0;
    }
    atomicAdd(&cnt, c);
    __syncthreads();
    if (threadIdx.x == 0) *flag = (2 * cnt > 4096) ? 1 : 0;
}

// ---------------------------------------------------------------------------
// Convert the 10 parameter arrays into canonical bf16, flag-branched.
// ---------------------------------------------------------------------------
__global__ __launch_bounds__(256) void convert_params(
    const void* tw, const void* tb, const void* pw, const void* pb,
    const void* gw, const void* gbi, const void* ww, const void* wb,
    const void* gamma, const void* beta,
    u16* __restrict__ dst, const int* __restrict__ flag)
{
    const void* srcs[10] = {tw, tb, pw, pb, gw, gbi, ww, wb, gamma, beta};
    const int ns[10] = {131072, 256, 131072, 256, 131072, 256, 131072, 512, 512, 512};
    int seg = blockIdx.y;
    int off = 0;
    for (int s = 0; s < 10; ++s) { if (s == seg) break; off += ns[s]; }
    const void* src = srcs[seg];
    int n = ns[seg];
    int i0 = (blockIdx.x * 256 + threadIdx.x) * 8;
    if (i0 >= n) return;
    const int fl = *flag;
    u16* d = dst + off;
    for (int k = 0; k < 8; ++k) {
        int i = i0 + k;
        if (i < n)
            d[i] = fl ? ((const u16*)src)[i] : f2b(((const float*)src)[i]);
    }
}

// ---------------------------------------------------------------------------
// x ingest + transpose: x [b,C,N] (fp32 or bf16) -> xT [b,N,C] bf16.
// ---------------------------------------------------------------------------
__global__ __launch_bounds__(256) void transpose_x(
    const void* __restrict__ in, u16* __restrict__ out,
    const int* __restrict__ flag)
{
    __shared__ u16 tile[64][68];
    const int fl = *flag;
    const int t = threadIdx.x;
    const long base = (long)blockIdx.z * (long)C_ * (long)N_;
    const int c0 = blockIdx.x * 64, r0 = blockIdx.y * 64;
    const int lr = t >> 3;
    const int lc = (t & 7) * 8;
#pragma unroll
    for (int j = 0; j < 2; ++j) {
        int rr = lr + 32 * j;
        long eoff = base + (long)(r0 + rr) * N_ + c0 + lc;
        u16 v[8] __attribute__((aligned(16)));
        if (fl) {
            const u16* pi = (const u16*)in + eoff;
            *(uint64_t*)&v[0] = *(const uint64_t*)pi;
            *(uint64_t*)&v[4] = *(const uint64_t*)(pi + 4);
        } else {
            const float* pi = (const float*)in + eoff;
            floatx4 a = *(const floatx4*)pi;
            floatx4 b4 = *(const floatx4*)(pi + 4);
#pragma unroll
            for (int k = 0; k < 4; ++k) { v[k] = f2b(a[k]); v[4 + k] = f2b(b4[k]); }
        }
        *(uint64_t*)&tile[rr][lc] = *(const uint64_t*)&v[0];
        *(uint64_t*)&tile[rr][lc + 4] = *(const uint64_t*)&v[4];
    }
    __syncthreads();
#pragma unroll
    for (int j = 0; j < 2; ++j) {
        int oc = lr + 32 * j;
        int ob = (t & 7) * 8;
        u16 vals[8] __attribute__((aligned(16)));
#pragma unroll
        for (int k = 0; k < 8; ++k) vals[k] = tile[ob + k][oc];
        u16* po = out + (long)blockIdx.z * N_ * C_ + (long)(c0 + oc) * C_ + r0 + ob;
        *(uint64_t*)po = *(const uint64_t*)vals;
        *(uint64_t*)(po + 4) = *(const uint64_t*)(vals + 4);
    }
}

// ---------------------------------------------------------------------------
// bf16 64x64 tile transpose: in [z][R][Cc] -> out [z][Cc][R]
// ---------------------------------------------------------------------------
__global__ __launch_bounds__(256) void transpose64(
    const u16* __restrict__ in, u16* __restrict__ out, int R, int Cc)
{
    __shared__ u16 tile[64][68];
    const int t = threadIdx.x;
    const long base = (long)blockIdx.z * (long)R * (long)Cc;
    const int c0 = blockIdx.x * 64, r0 = blockIdx.y * 64;
    const int lr = t >> 3;
    const int lc = (t & 7) * 8;
#pragma unroll
    for (int j = 0; j < 2; ++j) {
        int rr = lr + 32 * j;
        const u16* pi = in + base + (long)(r0 + rr) * Cc + c0 + lc;
        *(uint64_t*)&tile[rr][lc] = *(const uint64_t*)pi;
        *(uint64_t*)&tile[rr][lc + 4] = *(const uint64_t*)(pi + 4);
    }
    __syncthreads();
#pragma unroll
    for (int j = 0; j < 2; ++j) {
        int oc = lr + 32 * j;
        int ob = (t & 7) * 8;
        u16 vals[8] __attribute__((aligned(16)));
#pragma unroll
        for (int k = 0; k < 8; ++k) vals[k] = tile[ob + k][oc];
        u16* po = out + base + (long)(c0 + oc) * R + r0 + ob;
        *(uint64_t*)po = *(const uint64_t*)vals;
        *(uint64_t*)(po + 4) = *(const uint64_t*)(vals + 4);
    }
}

// ---------------------------------------------------------------------------
// gemm128: Out[m][n] = sum_k A[m][k]*Bt[n][k] + bias[n], all bf16.
// 128x128 tile, BK=32, 4 waves (64x64 quadrants, 4x4 MFMA frags).
// Fragment-order DMA staging (conflict-free 1KB ds_read_b128), dbuf.
// blockIdx.z selects weight set / output slab (fused projections):
//   Bt = BtBase + z*bstride, bias = biasBase + z*bstride,
//   Out = OutBase + z*ostride.
// grid = (M/128, ncols/128, nz), block = 256.
// ---------------------------------------------------------------------------
template<int K>
__global__ __launch_bounds__(256, 3) void gemm128(
    const u16* __restrict__ A,
    const u16* __restrict__ BtBase,
    const u16* __restrict__ biasBase,
    u16* __restrict__ OutBase,
    int ncols, long bstride, long ostride)
{
    __shared__ __attribute__((aligned(16))) u16 Asf[2][8][64][8];
    __shared__ __attribute__((aligned(16))) u16 Bsf[2][8][64][8];

    const int t = threadIdx.x;
    const int wave = t >> 6, lane = t & 63;
    const int q = lane >> 4, lx = lane & 15;
    const int m0 = blockIdx.x * 128;
    const int n0 = blockIdx.y * 128;
    const u16* Bt = BtBase + (long)blockIdx.z * bstride;
    const u16* bias = biasBase + (long)blockIdx.z * bstride;
    u16* Out = OutBase + (long)blockIdx.z * ostride;

    floatx4 zero4 = {0.f, 0.f, 0.f, 0.f};
    floatx4 acc[4][4];
#pragma unroll
    for (int i = 0; i < 4; ++i)
#pragma unroll
        for (int j = 0; j < 4; ++j) acc[i][j] = zero4;

    // wave stages rowgroups wave*2, wave*2+1 of both A and B
    auto stage = [&](int buf, int k0) {
#pragma unroll
        for (int i = 0; i < 2; ++i) {
            int rg = wave * 2 + i;
            gload_lds16(A + (long)(m0 + rg * 16 + lx) * K + k0 + q * 8,
                        &Asf[buf][rg][0][0]);
            gload_lds16(Bt + (long)(n0 + rg * 16 + lx) * K + k0 + q * 8,
                        &Bsf[buf][rg][0][0]);
        }
    };

    stage(0, 0);
    const int rg0 = (wave >> 1) * 4, cg0 = (wave & 1) * 4;
    const int NS = K / 32;
    for (int s = 0; s < NS; ++s) {
        const int buf = s & 1;
        __syncthreads();                 // drains DMA (vmcnt0) + block sync
        if (s + 1 < NS) stage(buf ^ 1, (s + 1) * 32);
        short8 af[4], bfr[4];
#pragma unroll
        for (int i = 0; i < 4; ++i)
            af[i] = *(const short8*)&Asf[buf][rg0 + i][lane][0];
#pragma unroll
        for (int j = 0; j < 4; ++j)
            bfr[j] = *(const short8*)&Bsf[buf][cg0 + j][lane][0];
#pragma unroll
        for (int i = 0; i < 4; ++i)
#pragma unroll
            for (int j = 0; j < 4; ++j)
                acc[i][j] = mfma16(af[i], bfr[j], acc[i][j]);
    }

    // epilogue: C/D layout col=lane&15, row=(lane>>4)*4+reg  [m89/m91]
    const int wr = (wave >> 1) * 64, wc = (wave & 1) * 64;
#pragma unroll
    for (int j = 0; j < 4; ++j) {
        int col = n0 + wc + j * 16 + lx;
        float bv = b2f(bias[col]);
#pragma unroll
        for (int i = 0; i < 4; ++i) {
#pragma unroll
            for (int r = 0; r < 4; ++r) {
                int row = m0 + wr + i * 16 + q * 4 + r;
                Out[(long)row * ncols + col] = f2b(acc[i][j][r] + bv);
            }
        }
    }
}

// ---------------------------------------------------------------------------
// Fused attention v4.1: r6 fragment-order tiles + r5-style batched S-phase
// fragment prefetch (8 reads in flight, then 16 MFMAs, x2 halves).
// Block = 128 Q-rows (4 waves x 32), m-step 32, z-split 2.
// grid = (25, B, 2), block = 256.
// ---------------------------------------------------------------------------
__global__ __launch_bounds__(256, 2) void attn(
    const u16* __restrict__ theta,   // [B][N][CI]
    const u16* __restrict__ phi,     // [B][N][CI]
    const u16* __restrict__ gT,      // [B][CI][N]
    u16* __restrict__ ypart,         // [2][B][N][CI] unnormalized (= d_out)
    float* __restrict__ lpart)       // [2][B][N] row exp-sums
{
    __shared__ __attribute__((aligned(16))) u16 psf[2][8][2][64][8];
    __shared__ __attribute__((aligned(16))) u16 gsf[2][16][64][8];
    __shared__ __attribute__((aligned(16))) u16 Ps[4][32][40];

    const int t = threadIdx.x;
    const int wave = t >> 6, lane = t & 63;
    const int q = lane >> 4, lx = lane & 15;
    const int b = blockIdx.y;
    const int z = blockIdx.z;
    const int n0w = blockIdx.x * 128 + wave * 32;
    const bool valid = n0w < N_;
    const u16* thb = theta + (long)b * N_ * CI_;
    const u16* phb = phi + (long)b * N_ * CI_;
    const u16* gb = gT + (long)b * CI_ * N_;

    // persistent theta A-frags: 2 row-halves x 8 k-chunks (64 VGPR)
    short8 tf[2][8];
#pragma unroll
    for (int h = 0; h < 2; ++h) {
        int trow = n0w + h * 16 + lx;
        if (trow >= N_) trow = N_ - 1;
#pragma unroll
        for (int kk = 0; kk < 8; ++kk)
            tf[h][kk] = *(const short8*)(thb + (long)trow * CI_ + kk * 32 + q * 8);
    }

    floatx4 zero4 = {0.f, 0.f, 0.f, 0.f};
    floatx4 yacc[2][16];
#pragma unroll
    for (int h = 0; h < 2; ++h)
#pragma unroll
        for (int i = 0; i < 16; ++i) yacc[h][i] = zero4;
    floatx4 lacc[2] = {zero4, zero4};
    const short8 ones = {0x3F80, 0x3F80, 0x3F80, 0x3F80,
                         0x3F80, 0x3F80, 0x3F80, 0x3F80};

    const int mbeg = z * (N_ / 2);

    // fragment-order gather: 8 DMA insts per wave per step
    auto stage = [&](int buf, int m0) {
#pragma unroll
        for (int i = 0; i < 2; ++i) {
            int kc = wave * 2 + i;
#pragma unroll
            for (int h = 0; h < 2; ++h)
                gload_lds16(phb + (long)(m0 + h * 16 + lx) * CI_ + kc * 32 + q * 8,
                            &psf[buf][kc][h][0][0]);
        }
#pragma unroll
        for (int j4 = 0; j4 < 4; ++j4) {
            int ct = wave * 4 + j4;
            gload_lds16(gb + (long)(ct * 16 + lx) * N_ + m0 + q * 8,
                        &gsf[buf][ct][0][0]);
        }
    };

    stage(0, mbeg);
    const int NSTEP = (N_ / 2) / 32;     // 49
    for (int s = 0; s < NSTEP; ++s) {
        const int buf = s & 1;
        __syncthreads();                 // drains DMA (vmcnt0) + block sync
        if (s + 1 < NSTEP) stage(buf ^ 1, mbeg + (s + 1) * 32);

        // ---- S = theta . phi^T : batched frag prefetch (r5 scheduling) ----
        floatx4 sacc[2][2];
        sacc[0][0] = zero4; sacc[0][1] = zero4;
        sacc[1][0] = zero4; sacc[1][1] = zero4;
#pragma unroll
        for (int half = 0; half < 2; ++half) {
            short8 pb0[4], pb1[4];
#pragma unroll
            for (int u = 0; u < 4; ++u) {
                int kk = half * 4 + u;
                pb0[u] = *(const short8*)&psf[buf][kk][0][lane][0];
                pb1[u] = *(const short8*)&psf[buf][kk][1][lane][0];
            }
#pragma unroll
            for (int u = 0; u < 4; ++u) {
                int kk = half * 4 + u;
                sacc[0][0] = mfma16(tf[0][kk], pb0[u], sacc[0][0]);
                sacc[1][0] = mfma16(tf[1][kk], pb0[u], sacc[1][0]);
                sacc[0][1] = mfma16(tf[0][kk], pb1[u], sacc[0][1]);
                sacc[1][1] = mfma16(tf[1][kk], pb1[u], sacc[1][1]);
            }
        }

        // ---- exp + pack P to A-layout via per-wave LDS ----
#pragma unroll
        for (int h = 0; h < 2; ++h)
#pragma unroll
            for (int mh = 0; mh < 2; ++mh)
#pragma unroll
                for (int r = 0; r < 4; ++r) {
                    float e = __expf(fminf(sacc[h][mh][r], 60.f));
                    Ps[wave][h * 16 + q * 4 + r][mh * 16 + lx] = f2b(e);
                }
        __builtin_amdgcn_wave_barrier();
        short8 pA0 = *(const short8*)&Ps[wave][lx][q * 8];
        short8 pA1 = *(const short8*)&Ps[wave][16 + lx][q * 8];
        __builtin_amdgcn_wave_barrier();

        // ---- PV: 16 conflict-free b128 reads, 32+2 MFMAs ----
#pragma unroll
        for (int ct = 0; ct < 16; ++ct) {
            short8 gf = *(const short8*)&gsf[buf][ct][lane][0];
            yacc[0][ct] = mfma16(pA0, gf, yacc[0][ct]);
            yacc[1][ct] = mfma16(pA1, gf, yacc[1][ct]);
        }
        lacc[0] = mfma16(pA0, ones, lacc[0]);
        lacc[1] = mfma16(pA1, ones, lacc[1]);
    }

    if (valid) {
        u16* yb = ypart + (long)z * B_ * N_ * CI_ + (long)b * N_ * CI_;
#pragma unroll
        for (int h = 0; h < 2; ++h)
#pragma unroll
            for (int ct = 0; ct < 16; ++ct)
#pragma unroll
                for (int r = 0; r < 4; ++r)
                    yb[(long)(n0w + h * 16 + q * 4 + r) * CI_ + ct * 16 + lx] =
                        f2b(yacc[h][ct][r]);
        if (lx == 0) {
#pragma unroll
            for (int h = 0; h < 2; ++h)
#pragma unroll
                for (int r = 0; r < 4; ++r)
                    lpart[(long)z * BN_ + (long)b * N_ + n0w + h * 16 + q * 4 + r] =
                        lacc[h][r];
        }
    }
}

// ---------------------------------------------------------------------------
// y = (y0 + y1) / (l0 + l1);  grid = BN_*32/256 = 3136 blocks
// ---------------------------------------------------------------------------
__global__ __launch_bounds__(256) void attn_combine(
    const u16* __restrict__ ypart, const float* __restrict__ lpart,
    u16* __restrict__ y)
{
    long tt = (long)blockIdx.x * 256 + threadIdx.x;
    long row = tt >> 5;
    int cb = (int)(tt & 31) * 8;
    float l = lpart[row] + lpart[BN_ + row];
    float rl = 1.0f / l;
    const u16* p0 = ypart + row * CI_ + cb;
    const u16* p1 = p0 + (long)B_ * N_ * CI_;
    short8 v0 = *(const short8*)p0;
    short8 v1 = *(const short8*)p1;
    u16 ov[8] __attribute__((aligned(16)));
#pragma unroll
    for (int j = 0; j < 8; ++j)
        ov[j] = f2b((b2f(((const u16*)&v0)[j]) + b2f(((const u16*)&v1)[j])) * rl);
    *(short8*)(y + row * CI_ + cb) = *(const short8*)ov;
}

// ---------------------------------------------------------------------------
// BN stats over bf16 wy [b,N,C]: per-block partials + atomics.
// ---------------------------------------------------------------------------
__global__ void zero_stats(float* stats) {
    stats[threadIdx.x] = 0.f;
    stats[threadIdx.x + 256] = 0.f;
    stats[threadIdx.x + 512] = 0.f;
    stats[threadIdx.x + 768] = 0.f;
}

__global__ __launch_bounds__(256) void bn_stats(
    const u16* __restrict__ wy, float* __restrict__ stats)
{
    const int t = threadIdx.x;
    const long row0 = (long)blockIdx.x * 256;
    float s0 = 0.f, s1 = 0.f, q0 = 0.f, q1 = 0.f;
    for (int r = 0; r < 256; ++r) {
        const u16* p = wy + (row0 + r) * C_;
        float a = b2f(p[t]), b = b2f(p[t + 256]);
        s0 += a; q0 += a * a;
        s1 += b; q1 += b * b;
    }
    atomicAdd(&stats[t], s0);
    atomicAdd(&stats[t + 256], s1);
    atomicAdd(&stats[C_ + t], q0);
    atomicAdd(&stats[C_ + t + 256], q1);
}

// ---------------------------------------------------------------------------
// out[b][c][n] = (wy[b][n][c]-mean)*rstd*gamma + beta + x[b][c][n]
// ---------------------------------------------------------------------------
__global__ __launch_bounds__(256) void bn_apply(
    const u16* __restrict__ wy, const void* __restrict__ xv,
    const u16* __restrict__ gamma, const u16* __restrict__ beta,
    const float* __restrict__ stats, void* __restrict__ outv,
    const int* __restrict__ flag)
{
    __shared__ float tile[64][65];
    const int fl = *flag;
    const int t = threadIdx.x;
    const int nb0 = blockIdx.x * 64;
    const int c0 = blockIdx.y * 64;
    const int b = blockIdx.z;
#pragma unroll
    for (int j = 0; j < 4; ++j) {
        int row = (t >> 4) + 16 * j;
        int col = (t & 15) * 4;
        const u16* p = wy + ((long)b * N_ + nb0 + row) * C_ + c0 + col;
        u16 lv[4] __attribute__((aligned(8)));
        *(uint64_t*)lv = *(const uint64_t*)p;
#pragma unroll
        for (int k = 0; k < 4; ++k) tile[row][col + k] = b2f(lv[k]);
    }
    __syncthreads();
    const float inv = 1.0f / (float)BN_;
#pragma unroll
    for (int it = 0; it < 8; ++it) {
        int oc = (t >> 5) + 8 * it;
        int on = (t & 31) * 2;
        int c = c0 + oc;
        float mean = stats[c] * inv;
        float var = stats[C_ + c] * inv - mean * mean;
        float rstd = rsqrtf(var + 1e-5f);
        float sc = b2f(gamma[c]) * rstd;
        float sh = b2f(beta[c]) - mean * sc;
        long base = ((long)b * C_ + c) * N_ + nb0 + on;
        float v0 = tile[on][oc] * sc + sh;
        float v1 = tile[on + 1][oc] * sc + sh;
        if (fl) {
            v0 += b2f(((const u16*)xv)[base]);
            v1 += b2f(((const u16*)xv)[base + 1]);
            ((u16*)outv)[base] = f2b(v0);
            ((u16*)outv)[base + 1] = f2b(v1);
        } else {
            v0 += ((const float*)xv)[base];
            v1 += ((const float*)xv)[base + 1];
            ((float*)outv)[base] = v0;
            ((float*)outv)[base + 1] = v1;
        }
    }
}

// ---------------------------------------------------------------------------
extern "C" void kernel_launch(void* const* d_in, const int* in_sizes, int n_in,
                              void* d_out, int out_size, void* d_ws, size_t ws_size,
                              hipStream_t stream)
{
    (void)in_sizes; (void)n_in; (void)out_size; (void)ws_size;

    const size_t S = 12845056;               // one [B,N,CI] bf16 slab (bytes)
    char* base = (char*)d_ws;
    u16*   xT    = (u16*)(base);             // [0, 2S)   steps 1-2
    u16*   gT    = (u16*)(base);             // [0, S)    steps 3-4
    u16*   y     = (u16*)(base + S);         // [S, 2S)   steps 5-6
    u16*   th    = (u16*)(base + 2 * S);     // [2S, 3S)  steps 2-4
    u16*   wy    = (u16*)(base + 2 * S);     // [2S, 4S)  steps 6-8
    u16*   gn    = (u16*)(base + 4 * S);     // [4S, 5S)  steps 2-3
    float* lpart = (float*)(base + 5 * S);
    float* stats = (float*)(base + 5 * S + (size_t)2 * BN_ * 4);
    u16*   cw    = (u16*)(base + 5 * S + (size_t)2 * BN_ * 4 + 4096);
    int*   flag  = (int*)(base + 5 * S + (size_t)2 * BN_ * 4 + 4096 + 1055744);

    // canonical param layout: [tw|tb][pw|pb][gw|gb][ww|wb][gamma][beta]
    // weight-set stride = 131072 + 256 = 131328 u16 (tw->pw->gw)
    u16* ctw = cw;               u16* ctb = cw + 131072;
    u16* cpw = ctb + 256;        u16* cpb = cpw + 131072;
    u16* cgw = cpb + 256;        u16* cgb = cgw + 131072;
    u16* cww = cgb + 256;        u16* cwb = cww + 131072;
    u16* cga = cwb + 512;        u16* cbe = cga + 512;
    (void)cpw; (void)cpb; (void)cgw; (void)cgb;

    u16* ypart = (u16*)d_out;    // scratch, dead before bn_apply overwrites

    detect_dtype<<<1, 256, 0, stream>>>((const u32*)d_in[0], flag);
    convert_params<<<dim3(64, 10), 256, 0, stream>>>(
        d_in[1], d_in[2], d_in[3], d_in[4], d_in[5], d_in[6], d_in[7],
        d_in[8], d_in[9], d_in[10], cw, flag);

    transpose_x<<<dim3(N_ / 64, C_ / 64, B_), 256, 0, stream>>>(d_in[0], xT, flag);

    // fused theta/phi/g projections: z selects weight set + output slab
    gemm128<C_><<<dim3(BN_ / 128, CI_ / 128, 3), 256, 0, stream>>>(
        xT, ctw, ctb, th, CI_, 131328L, (long)(S / 2));

    transpose64<<<dim3(CI_ / 64, N_ / 64, B_), 256, 0, stream>>>(gn, gT, N_, CI_);

    attn<<<dim3(25, B_, 2), 256, 0, stream>>>(th, th + S / 2, gT, ypart, lpart);

    attn_combine<<<dim3((BN_ * 32) / 256), 256, 0, stream>>>(ypart, lpart, y);

    // W GEMM: [25088,256] x [512,256]^T -> wy bf16 [25088,512]
    gemm128<CI_><<<dim3(BN_ / 128, C_ / 128, 1), 256, 0, stream>>>(
        y, cww, cwb, wy, C_, 0L, 0L);

    zero_stats<<<1, 256, 0, stream>>>(stats);
    bn_stats<<<BN_ / 256, 256, 0, stream>>>(wy, stats);

    bn_apply<<<dim3(N_ / 64, C_ / 64, B_), 256, 0, stream>>>(
        wy, d_in[0], cga, cbe, stats, d_out, flag);
}